// Round 1
// baseline (1677.112 us; speedup 1.0000x reference)
//
#include <hip/hip_runtime.h>
#include <math.h>

// Problem constants (fixed-shape problem)
#define B_  16
#define D_  37
#define F_  4096
#define I_  64
#define EPS 1e-5f

// ---------------------------------------------------------------------------
// Kernel 1: qkv projection + parameter-free LayerNorm.
// One wave (64 lanes) per (b, f): lane i computes h_i = sum_d x[b,d,f]*W[d,i],
// then wave-wide mean/var via shuffles. W staged in LDS (28.4 KB).
// ---------------------------------------------------------------------------
__global__ __launch_bounds__(256) void qkv_ln_k(
    const float* __restrict__ x,
    const float* __restrict__ Wq, const float* __restrict__ Wk,
    const float* __restrict__ Wv,
    float* __restrict__ qn, float* __restrict__ kn, float* __restrict__ vn) {
  __shared__ float sW[3 * D_ * I_];  // 3*37*64 floats = 28.4 KB
  const int t = threadIdx.x;
  for (int idx = t; idx < D_ * I_; idx += 256) {
    sW[idx]               = Wq[idx];
    sW[D_ * I_ + idx]     = Wk[idx];
    sW[2 * D_ * I_ + idx] = Wv[idx];
  }
  __syncthreads();

  const int wid  = t >> 6;
  const int lane = t & 63;
  const int bf   = blockIdx.x * 4 + wid;      // 0 .. 65535
  const int b    = bf >> 12;                  // /4096
  const int f    = bf & 4095;

  const float* xp = x + (size_t)b * D_ * F_ + f;
  float aq = 0.f, ak = 0.f, av = 0.f;
#pragma unroll
  for (int d = 0; d < D_; ++d) {
    const float xv = xp[(size_t)d * F_];      // wave-uniform broadcast load
    aq = fmaf(xv, sW[d * I_ + lane], aq);
    ak = fmaf(xv, sW[D_ * I_ + d * I_ + lane], ak);
    av = fmaf(xv, sW[2 * D_ * I_ + d * I_ + lane], av);
  }

  // LayerNorm over the 64 lanes of the wave
  auto lnorm = [&](float a) -> float {
    float s = a;
#pragma unroll
    for (int o = 32; o > 0; o >>= 1) s += __shfl_xor(s, o, 64);
    const float mu = s * (1.f / 64.f);
    const float d0 = a - mu;
    float v = d0 * d0;
#pragma unroll
    for (int o = 32; o > 0; o >>= 1) v += __shfl_xor(v, o, 64);
    v *= (1.f / 64.f);
    return d0 * rsqrtf(v + EPS);
  };

  const size_t oi = (size_t)bf * I_ + lane;
  qn[oi] = lnorm(aq);
  kn[oi] = lnorm(ak);
  vn[oi] = lnorm(av);
}

// ---------------------------------------------------------------------------
// LDS tile loaders. 64x64 fp32 tile, 256 threads, fully-coalesced float4
// global reads (4 consecutive rows = 1 KB contiguous per wave).
// load_tile_T stores transposed [i][r] (for b128 fragment reads in the
// outer-product loops); load_tile_N stores natural [r][i].
// ---------------------------------------------------------------------------
#define LDP 68  // padded stride: keeps float4 alignment, breaks write conflicts

__device__ __forceinline__ void load_tile_T(float dst[64][LDP],
                                            const float* __restrict__ src,
                                            int t) {
  const int i4 = t & 15;        // float4 index within the 64-float row
  const int r0 = t >> 4;        // 0..15
#pragma unroll
  for (int p = 0; p < 4; ++p) {
    const int r = p * 16 + r0;  // row index (k or q)
    const float4 v = *(const float4*)(src + (size_t)r * 64 + i4 * 4);
    dst[i4 * 4 + 0][r] = v.x;
    dst[i4 * 4 + 1][r] = v.y;
    dst[i4 * 4 + 2][r] = v.z;
    dst[i4 * 4 + 3][r] = v.w;
  }
}

__device__ __forceinline__ void load_tile_N(float dst[64][LDP],
                                            const float* __restrict__ src,
                                            int t) {
  const int i4 = t & 15;
  const int r0 = t >> 4;
#pragma unroll
  for (int p = 0; p < 4; ++p) {
    const int r = p * 16 + r0;
    *(float4*)&dst[r][i4 * 4] = *(const float4*)(src + (size_t)r * 64 + i4 * 4);
  }
}

// ---------------------------------------------------------------------------
// Kernel 2: per-(b,k) column softmax stats over the query axis.
// Block = (b, 64-k tile); K tile resident transposed in LDS; loop q-chunks of
// 64: register-tiled 4x4 S computation, online (m, Z) per thread-column,
// final cross-ty reduction in LDS.
// ---------------------------------------------------------------------------
__global__ __launch_bounds__(256) void attn_stats_k(
    const float* __restrict__ qn, const float* __restrict__ kn,
    float* __restrict__ mk, float* __restrict__ rzk) {
  __shared__ float KT[64][LDP];   // [i][k]
  __shared__ float QT[64][LDP];   // [i][q]
  __shared__ float redM[64][17];
  __shared__ float redZ[64][17];

  const int t  = threadIdx.x;
  const int b  = blockIdx.y;
  const int k0 = blockIdx.x * 64;
  const int tx = t & 15;          // k sub-tile
  const int ty = t >> 4;          // q sub-tile

  load_tile_T(KT, kn + ((size_t)b * F_ + k0) * I_, t);

  float m[4], Z[4];
#pragma unroll
  for (int l = 0; l < 4; ++l) { m[l] = -INFINITY; Z[l] = 0.f; }

  const float* qb = qn + (size_t)b * F_ * I_;
  for (int q0 = 0; q0 < F_; q0 += 64) {
    __syncthreads();              // prior S-loop reads of QT done
    load_tile_T(QT, qb + (size_t)q0 * I_, t);
    __syncthreads();              // QT (and, 1st iter, KT) visible

    float s[4][4] = {};
#pragma unroll 4
    for (int i = 0; i < 64; ++i) {
      const float4 qv = *(const float4*)&QT[i][ty * 4];
      const float4 kv = *(const float4*)&KT[i][tx * 4];
      const float qf[4] = {qv.x, qv.y, qv.z, qv.w};
      const float kf[4] = {kv.x, kv.y, kv.z, kv.w};
#pragma unroll
      for (int j = 0; j < 4; ++j)
#pragma unroll
        for (int l = 0; l < 4; ++l) s[j][l] = fmaf(qf[j], kf[l], s[j][l]);
    }

#pragma unroll
    for (int l = 0; l < 4; ++l) {
#pragma unroll
      for (int j = 0; j < 4; ++j) {
        const float v  = s[j][l] * 0.125f;
        const float mn = fmaxf(m[l], v);
        Z[l] = fmaf(Z[l], __expf(m[l] - mn), __expf(v - mn));
        m[l] = mn;
      }
    }
  }

#pragma unroll
  for (int l = 0; l < 4; ++l) {
    redM[tx * 4 + l][ty] = m[l];
    redZ[tx * 4 + l][ty] = Z[l];
  }
  __syncthreads();
  if (t < 64) {
    float M = -INFINITY;
#pragma unroll
    for (int y = 0; y < 16; ++y) M = fmaxf(M, redM[t][y]);
    float Zs = 0.f;
#pragma unroll
    for (int y = 0; y < 16; ++y) Zs += redZ[t][y] * __expf(redM[t][y] - M);
    mk[(size_t)b * F_ + k0 + t]  = M;
    rzk[(size_t)b * F_ + k0 + t] = 1.f / Zs;
  }
}

// ---------------------------------------------------------------------------
// Kernel 3: out[b,q,i] = sum_k exp(att[q,k]-m_k)/Z_k * v[k,i].
// Block = (b, 64-q tile). Per k-chunk: recompute S (4x4 register tile),
// write W transposed [k][q] to LDS, then accumulate the second GEMM.
// K-tile and V-tile alias one LDS buffer (extra barrier) to stay < 64 KB.
// ---------------------------------------------------------------------------
__global__ __launch_bounds__(256) void attn_out_k(
    const float* __restrict__ qn, const float* __restrict__ kn,
    const float* __restrict__ vn, const float* __restrict__ mk,
    const float* __restrict__ rzk, float* __restrict__ out) {
  __shared__ float QT[64][LDP];   // [i][q], resident
  __shared__ float KV[64][LDP];   // K transposed [i][k], then V natural [k][i]
  __shared__ float WT[64][LDP];   // [k][q]
  __shared__ float mS[64], rzS[64];

  const int t  = threadIdx.x;
  const int b  = blockIdx.y;
  const int q0 = blockIdx.x * 64;
  const int tx = t & 15;          // i (and k sub-tile in S loop)
  const int ty = t >> 4;          // q sub-tile

  load_tile_T(QT, qn + ((size_t)b * F_ + q0) * I_, t);

  float o[4][4] = {};

  for (int k0 = 0; k0 < F_; k0 += 64) {
    __syncthreads();              // prior acc-loop reads of KV/WT done
    load_tile_T(KV, kn + ((size_t)b * F_ + k0) * I_, t);
    if (t < 64) {
      mS[t]  = mk[(size_t)b * F_ + k0 + t];
      rzS[t] = rzk[(size_t)b * F_ + k0 + t];
    }
    __syncthreads();              // KV=K^T, stats (and 1st iter QT) visible

    float s[4][4] = {};
#pragma unroll 4
    for (int i = 0; i < 64; ++i) {
      const float4 qv = *(const float4*)&QT[i][ty * 4];
      const float4 kv = *(const float4*)&KV[i][tx * 4];
      const float qf[4] = {qv.x, qv.y, qv.z, qv.w};
      const float kf[4] = {kv.x, kv.y, kv.z, kv.w};
#pragma unroll
      for (int j = 0; j < 4; ++j)
#pragma unroll
        for (int l = 0; l < 4; ++l) s[j][l] = fmaf(qf[j], kf[l], s[j][l]);
    }

    // w[q,k] = exp(s*scale - m_k) * (1/Z_k), stored transposed [k][q]
#pragma unroll
    for (int l = 0; l < 4; ++l) {
      const float mv = mS[tx * 4 + l];
      const float rz = rzS[tx * 4 + l];
#pragma unroll
      for (int j = 0; j < 4; ++j) {
        WT[tx * 4 + l][ty * 4 + j] = __expf(fmaf(s[j][l], 0.125f, -mv)) * rz;
      }
    }
    __syncthreads();              // WT complete; KV=K^T no longer needed
    load_tile_N(KV, vn + ((size_t)b * F_ + k0) * I_, t);
    __syncthreads();              // KV=V visible

#pragma unroll 4
    for (int k = 0; k < 64; ++k) {
      const float4 wv = *(const float4*)&WT[k][ty * 4];
      const float4 vv = *(const float4*)&KV[k][tx * 4];
      const float wf[4] = {wv.x, wv.y, wv.z, wv.w};
      const float vf[4] = {vv.x, vv.y, vv.z, vv.w};
#pragma unroll
      for (int j = 0; j < 4; ++j)
#pragma unroll
        for (int l = 0; l < 4; ++l) o[j][l] = fmaf(wf[j], vf[l], o[j][l]);
    }
  }

  float* ob = out + ((size_t)b * F_ + q0) * I_;
#pragma unroll
  for (int j = 0; j < 4; ++j) {
    float4 v;
    v.x = o[j][0]; v.y = o[j][1]; v.z = o[j][2]; v.w = o[j][3];
    *(float4*)&ob[(size_t)(ty * 4 + j) * I_ + tx * 4] = v;
  }
}

// ---------------------------------------------------------------------------
extern "C" void kernel_launch(void* const* d_in, const int* in_sizes, int n_in,
                              void* d_out, int out_size, void* d_ws,
                              size_t ws_size, hipStream_t stream) {
  const float* x  = (const float*)d_in[0];
  const float* Wq = (const float*)d_in[1];
  const float* Wk = (const float*)d_in[2];
  const float* Wv = (const float*)d_in[3];
  float* out = (float*)d_out;

  // workspace layout (floats): qn, kn, vn [B*F*I each], mk, rzk [B*F each]
  float* qn  = (float*)d_ws;
  float* kn  = qn + (size_t)B_ * F_ * I_;
  float* vn  = kn + (size_t)B_ * F_ * I_;
  float* mk  = vn + (size_t)B_ * F_ * I_;
  float* rzk = mk + (size_t)B_ * F_;

  qkv_ln_k<<<dim3(B_ * F_ / 4), 256, 0, stream>>>(x, Wq, Wk, Wv, qn, kn, vn);
  attn_stats_k<<<dim3(F_ / 64, B_), 256, 0, stream>>>(qn, kn, mk, rzk);
  attn_out_k<<<dim3(F_ / 64, B_), 256, 0, stream>>>(qn, kn, vn, mk, rzk, out);
}

// Round 2
// 358.696 us; speedup vs baseline: 4.6756x; 4.6756x over previous
//
#include <hip/hip_runtime.h>
#include <math.h>

// Problem constants (fixed-shape problem)
#define B_  16
#define D_  37
#define F_  4096
#define I_  64
#define EPS 1e-5f
// softmax scale 1/sqrt(64) folded with log2(e) into q at projection time,
// so S_mfma = att*log2e and softmax is a raw exp2.
#define QSCALE 0.18033688011112042f

typedef unsigned short u16;
typedef __bf16 bf16x8 __attribute__((ext_vector_type(8)));
typedef float  f32x16 __attribute__((ext_vector_type(16)));

#define ZERO16 {0,0,0,0, 0,0,0,0, 0,0,0,0, 0,0,0,0}
#define MFMA32(a, b, c) __builtin_amdgcn_mfma_f32_32x32x16_bf16((a), (b), (c), 0, 0, 0)

// fp32 -> bf16 (RNE), bit-level (no header dependences)
__device__ __forceinline__ u16 f2b(float f) {
  unsigned u = __builtin_bit_cast(unsigned, f);
  return (u16)((u + 0x7fffu + ((u >> 16) & 1u)) >> 16);
}

// ---------------------------------------------------------------------------
// Swizzled LDS tiles: logical [rows][64] bf16, elem (r,c) stored at
//   r*64 + ((c>>3 ^ (r&7))<<3) + (c&7)
// -> 16B-aligned b128 fragment reads AND conflict-free banks (XOR swizzle,
//    CK-style) without padding (padding breaks b128 alignment).
// ---------------------------------------------------------------------------
__device__ __forceinline__ bf16x8 ldfrag(const u16* base, int row, int kb) {
  return *(const bf16x8*)(base + (row << 6) + ((kb ^ (row & 7)) << 3));
}
// stage one 16B chunk c (8 bf16) of a [rows][64] tile from global (row pitch
// spitch elems) into the swizzled LDS tile. Coalesced: 8 lanes = 128B run.
__device__ __forceinline__ void stage16(u16* dst, const u16* src, int c, int spitch) {
  const int r = c >> 3, cb = c & 7;
  const int4 v = *(const int4*)(src + (size_t)r * spitch + (cb << 3));
  *(int4*)(dst + (r << 6) + ((cb ^ (r & 7)) << 3)) = v;
}

// ---------------------------------------------------------------------------
// Kernel 1: qkv projection + LayerNorm -> bf16. q pre-scaled by QSCALE.
// v written transposed vt[b][i][f] (via LDS tile) for kernel 3's B-fragments.
// Block: (b, 64-f tile), 4 waves x 16 f-iterations, lane = i.
// ---------------------------------------------------------------------------
__global__ __launch_bounds__(256) void qkv_ln_k(
    const float* __restrict__ x,
    const float* __restrict__ Wq, const float* __restrict__ Wk,
    const float* __restrict__ Wv,
    u16* __restrict__ qn, u16* __restrict__ kn, u16* __restrict__ vt) {
  __shared__ float sW[3 * D_ * I_];                 // 28.4 KB
  __shared__ float xs[D_ * 64];                     // 9.5 KB
  __shared__ __align__(16) u16 vtile[64 * 72];      // 9.2 KB, stride 72 (16B rows)

  const int t = threadIdx.x;
  const int b = blockIdx.y;
  const int f0 = blockIdx.x * 64;

  for (int i = t; i < D_ * I_; i += 256) {
    sW[i]             = Wq[i];
    sW[D_ * I_ + i]   = Wk[i];
    sW[2 * D_ * I_ + i] = Wv[i];
  }
  const float* xb = x + (size_t)b * D_ * F_ + f0;
  for (int i = t; i < D_ * 64; i += 256)
    xs[i] = xb[(size_t)(i >> 6) * F_ + (i & 63)];
  __syncthreads();

  const int lane = t & 63, w = t >> 6;

  for (int it = 0; it < 16; ++it) {
    const int fl = w * 16 + it;
    float hq = 0.f, hk = 0.f, hv = 0.f;
#pragma unroll
    for (int d = 0; d < D_; ++d) {
      const float xv = xs[d * 64 + fl];             // wave-uniform broadcast
      hq = fmaf(xv, sW[d * 64 + lane], hq);
      hk = fmaf(xv, sW[D_ * I_ + d * 64 + lane], hk);
      hv = fmaf(xv, sW[2 * D_ * I_ + d * 64 + lane], hv);
    }
    auto lnorm = [&](float a) -> float {
      float s = a;
#pragma unroll
      for (int o = 32; o > 0; o >>= 1) s += __shfl_xor(s, o, 64);
      const float mu = s * (1.f / 64.f);
      const float d0 = a - mu;
      float v = d0 * d0;
#pragma unroll
      for (int o = 32; o > 0; o >>= 1) v += __shfl_xor(v, o, 64);
      return d0 * rsqrtf(v * (1.f / 64.f) + EPS);
    };
    const size_t fo = ((size_t)b * F_ + f0 + fl) * I_ + lane;
    qn[fo] = f2b(lnorm(hq) * QSCALE);
    kn[fo] = f2b(lnorm(hk));
    vtile[lane * 72 + fl] = f2b(lnorm(hv));
  }
  __syncthreads();
  // bulk-write vtile -> vt[b][i][f0..f0+63], 16B per thread-chunk
  for (int p = 0; p < 2; ++p) {
    const int c = p * 256 + t;                      // 0..511
    const int r = c >> 3, off = (c & 7) * 8;
    const int4 v = *(const int4*)&vtile[r * 72 + off];
    *(int4*)(vt + ((size_t)b * I_ + r) * F_ + f0 + off) = v;
  }
}

// ---------------------------------------------------------------------------
// Kernel 2: column-softmax stats. Z_k = sum_q exp2(S_mfma[q,k]); lzk = -log2 Z.
// No max pass needed: LN rows have norm exactly 8 -> |att|<=8 -> exp2<=2^11.6.
// Block: (b, 128-k tile). K resident in LDS; wave w owns k rows w*32..w*32+31.
// Stream q in 64-chunks: 2 q-blocks x own-k MFMA, exp2-accumulate per lane
// (lane&31 = fixed column), lane-pair combine at the end.
// ---------------------------------------------------------------------------
__global__ __launch_bounds__(256) void attn_stats_k(
    const u16* __restrict__ qn, const u16* __restrict__ kn,
    float* __restrict__ lzk) {
  __shared__ __align__(16) u16 Ks[128 * 64];        // 16 KB
  __shared__ __align__(16) u16 Qs[64 * 64];         // 8 KB

  const int t = threadIdx.x, lane = t & 63, w = t >> 6;
  const int b = blockIdx.y, k0 = blockIdx.x * 128;
  const int l31 = lane & 31, lh = lane >> 5;

  const u16* kb = kn + ((size_t)b * F_ + k0) * I_;
  for (int p = 0; p < 4; ++p) stage16(Ks, kb, p * 256 + t, 64);

  const u16* qb = qn + (size_t)b * F_ * I_;
  const u16* myK = Ks + (w * 32) * 64;              // w*32 % 8 == 0: swizzle consistent
  float Z = 0.f;

  for (int q0 = 0; q0 < F_; q0 += 64) {
    __syncthreads();                                // prev Qs reads done (1st: Ks visible)
    for (int p = 0; p < 2; ++p) stage16(Qs, qb + (size_t)q0 * I_, p * 256 + t, 64);
    __syncthreads();

    f32x16 a0 = ZERO16, a1 = ZERO16;
#pragma unroll
    for (int ic = 0; ic < 4; ++ic) {
      const bf16x8 bf  = ldfrag(myK, l31, ic * 2 + lh);
      const bf16x8 q0f = ldfrag(Qs, l31, ic * 2 + lh);
      const bf16x8 q1f = ldfrag(Qs + 32 * 64, l31, ic * 2 + lh);
      a0 = MFMA32(q0f, bf, a0);
      a1 = MFMA32(q1f, bf, a1);
    }
#pragma unroll
    for (int r = 0; r < 16; ++r) { Z += exp2f(a0[r]); Z += exp2f(a1[r]); }
  }

  Z += __shfl_xor(Z, 32, 64);
  if (lane < 32) lzk[(size_t)b * F_ + k0 + w * 32 + lane] = -log2f(Z);
}

// ---------------------------------------------------------------------------
// Kernel 3: out[q,i] = sum_k exp2(S+lz_k) * v[k,i]. Block: (b, 128-q tile),
// wave w owns q rows w*32..+31 (its S rows == its output rows -> P region is
// per-wave, no cross-wave barrier between P write and PV read).
// Per 64-k chunk: stage K,VT; S-MFMA; p=exp2(s+lz) -> bf16 -> own LDS P;
// PV-MFMA accumulate. 2 barriers/chunk.
// ---------------------------------------------------------------------------
__global__ __launch_bounds__(256) void attn_out_k(
    const u16* __restrict__ qn, const u16* __restrict__ kn,
    const u16* __restrict__ vt, const float* __restrict__ lzk,
    float* __restrict__ out) {
  __shared__ __align__(16) u16 Qs[128 * 64];        // 16 KB, resident
  __shared__ __align__(16) u16 Ks[64 * 64];         // 8 KB
  __shared__ __align__(16) u16 VTs[64 * 64];        // 8 KB  [i][k]
  __shared__ __align__(16) u16 Ps[4 * 32 * 64];     // 16 KB, per-wave regions
  __shared__ float lzs[64];

  const int t = threadIdx.x, lane = t & 63, w = t >> 6;
  const int b = blockIdx.y, q0 = blockIdx.x * 128;
  const int l31 = lane & 31, lh = lane >> 5;

  const u16* qb = qn + ((size_t)b * F_ + q0) * I_;
  for (int p = 0; p < 4; ++p) stage16(Qs, qb, p * 256 + t, 64);

  const u16* kbase = kn + (size_t)b * F_ * I_;
  const u16* vbase = vt + (size_t)b * I_ * F_;
  u16* Pw = Ps + w * (32 * 64);
  const u16* myQ = Qs + (w * 32) * 64;

  f32x16 o0 = ZERO16, o1 = ZERO16;

  for (int k0 = 0; k0 < F_; k0 += 64) {
    __syncthreads();                                // prev Ks/VTs reads done
    for (int p = 0; p < 2; ++p) stage16(Ks, kbase + (size_t)k0 * I_, p * 256 + t, 64);
    for (int p = 0; p < 2; ++p) stage16(VTs, vbase + k0, p * 256 + t, F_);
    if (t < 64) lzs[t] = lzk[(size_t)b * F_ + k0 + t];
    __syncthreads();

    // S = Q(own 32q) x K^T -> two 32x32 blocks (k-halves)
    f32x16 s0 = ZERO16, s1 = ZERO16;
#pragma unroll
    for (int ic = 0; ic < 4; ++ic) {
      const bf16x8 aq  = ldfrag(myQ, l31, ic * 2 + lh);
      const bf16x8 bk0 = ldfrag(Ks, l31, ic * 2 + lh);
      const bf16x8 bk1 = ldfrag(Ks + 32 * 64, l31, ic * 2 + lh);
      s0 = MFMA32(aq, bk0, s0);
      s1 = MFMA32(aq, bk1, s1);
    }

    // P = exp2(s + lz_k) -> bf16 into own wave's P region (swizzled [q][k])
    const float lz0 = lzs[l31], lz1 = lzs[32 + l31];
#pragma unroll
    for (int r = 0; r < 16; ++r) {
      const int qr = (r & 3) + 8 * (r >> 2) + 4 * lh;   // C/D row mapping
      const int ka = l31, kb2 = 32 + l31;
      Pw[(qr << 6) + (((ka >> 3) ^ (qr & 7)) << 3) + (ka & 7)]   = f2b(exp2f(s0[r] + lz0));
      Pw[(qr << 6) + (((kb2 >> 3) ^ (qr & 7)) << 3) + (kb2 & 7)] = f2b(exp2f(s1[r] + lz1));
    }
    // same-wave LDS write->read: compiler-inserted lgkmcnt wait, no barrier

    // O += P(32q x 64k) * V(64k x 64i), two i-halves
#pragma unroll
    for (int kc = 0; kc < 4; ++kc) {
      const bf16x8 ap  = ldfrag(Pw, l31, kc * 2 + lh);
      const bf16x8 bv0 = ldfrag(VTs, l31, kc * 2 + lh);
      const bf16x8 bv1 = ldfrag(VTs + 32 * 64, l31, kc * 2 + lh);
      o0 = MFMA32(ap, bv0, o0);
      o1 = MFMA32(ap, bv1, o1);
    }
  }

  float* ob = out + ((size_t)b * F_ + q0 + w * 32) * I_;
#pragma unroll
  for (int r = 0; r < 16; ++r) {
    const int qr = (r & 3) + 8 * (r >> 2) + 4 * lh;
    ob[(size_t)qr * I_ + l31]      = o0[r];
    ob[(size_t)qr * I_ + 32 + l31] = o1[r];
  }
}

// ---------------------------------------------------------------------------
extern "C" void kernel_launch(void* const* d_in, const int* in_sizes, int n_in,
                              void* d_out, int out_size, void* d_ws,
                              size_t ws_size, hipStream_t stream) {
  const float* x  = (const float*)d_in[0];
  const float* Wq = (const float*)d_in[1];
  const float* Wk = (const float*)d_in[2];
  const float* Wv = (const float*)d_in[3];
  float* out = (float*)d_out;

  // workspace: qn, kn (bf16 [b][f][64]); vt (bf16 [b][i][4096]); lzk (f32 [b][f])
  u16* qn   = (u16*)d_ws;
  u16* kn   = qn + (size_t)B_ * F_ * I_;
  u16* vt   = kn + (size_t)B_ * F_ * I_;
  float* lzk = (float*)(vt + (size_t)B_ * F_ * I_);

  qkv_ln_k<<<dim3(F_ / 64, B_), 256, 0, stream>>>(x, Wq, Wk, Wv, qn, kn, vt);
  attn_stats_k<<<dim3(F_ / 128, B_), 256, 0, stream>>>(qn, kn, lzk);
  attn_out_k<<<dim3(F_ / 128, B_), 256, 0, stream>>>(qn, kn, vt, lzk, out);
}